// Round 2
// baseline (2341.180 us; speedup 1.0000x reference)
//
#include <hip/hip_runtime.h>

// DecoderLSTM (show-attend-tell) for MI355X. Dtype-ADAPTIVE: detects at
// runtime whether float tensors are fp32 or bf16 (harness ambiguity), then
// canonicalizes everything to bf16 workspace buffers and runs bf16 MFMA.
// B=64 T=32 F=512 L=196 E=512 H=512 A=512 V=10000, Tmax=31.

typedef unsigned short ushort_t;
typedef __attribute__((ext_vector_type(8))) short short8;
typedef __attribute__((ext_vector_type(4))) float f32x4;

__device__ __forceinline__ float bf2f(ushort_t u) {
    unsigned x = ((unsigned)u) << 16;
    float f;
    __builtin_memcpy(&f, &x, 4);
    return f;
}
__device__ __forceinline__ ushort_t f2bf(float f) {
    unsigned x;
    __builtin_memcpy(&x, &f, 4);
    unsigned r = (x + 0x7fffu + ((x >> 16) & 1u)) >> 16;
    return (ushort_t)r;
}
__device__ __forceinline__ float sigmoidf_(float x) { return 1.f / (1.f + __expf(-x)); }
__device__ __forceinline__ float tanh_fast(float x) {
    float e = __expf(2.f * x);
    return 1.f - 2.f / (e + 1.f);
}
__device__ __forceinline__ float wred_sum(float v) {
    #pragma unroll
    for (int m = 32; m; m >>= 1) v += __shfl_xor(v, m, 64);
    return v;
}
__device__ __forceinline__ float wred_max(float v) {
    #pragma unroll
    for (int m = 32; m; m >>= 1) v = fmaxf(v, __shfl_xor(v, m, 64));
    return v;
}

// ---- dtype detection: low 16 bits of fp32 words have uniform bit stats;
// ---- of packed-bf16 pairs they are bf16 values with exponent near 127.
__global__ void detect_kernel(const unsigned* __restrict__ feat_raw, int* __restrict__ flag) {
    int lane = threadIdx.x;
    unsigned u = feat_raw[lane];
    unsigned e = (u >> 7) & 0xffu;
    bool bf_like = (e >= 105 && e <= 133);
    unsigned long long m = __ballot(bf_like);
    if (lane == 0) *flag = (__popcll(m) >= 40) ? 0 : 1;  // 1 -> fp32 inputs
}

#define NCVT 19
struct CvtArgs {
    const void* src[NCVT];
    void* dst[NCVT];
    int n[NCVT];
};

__global__ __launch_bounds__(256) void convert_kernel(CvtArgs a, const int* __restrict__ flag) {
    const int ai = blockIdx.y;
    const int n = a.n[ai];
    const int base = (blockIdx.x * 256 + threadIdx.x) * 8;
    if (base >= n) return;
    ushort_t* dst = (ushort_t*)a.dst[ai];
    if (*flag) {
        const float* s = (const float*)a.src[ai];
        #pragma unroll
        for (int i = 0; i < 8; ++i) {
            int idx = base + i;
            if (idx < n) dst[idx] = f2bf(s[idx]);
        }
    } else {
        const ushort_t* s = (const ushort_t*)a.src[ai];
        #pragma unroll
        for (int i = 0; i < 8; ++i) {
            int idx = base + i;
            if (idx < n) dst[idx] = s[idx];
        }
    }
}

// ---- gather needed embedding rows -> bf16 [31*64, 512] ----
__global__ __launch_bounds__(256) void embrows_kernel(const void* __restrict__ Wemb,
                                                      const int* __restrict__ captions,
                                                      const int* __restrict__ flag,
                                                      ushort_t* __restrict__ emb_c) {
    const int tb = blockIdx.x;  // t*64 + b
    const int t = tb >> 6, b = tb & 63;
    const int cap = captions[b * 32 + t];
    const int e0 = threadIdx.x;
    if (*flag) {
        const float* s = (const float*)Wemb + cap * 512;
        emb_c[tb * 512 + e0] = f2bf(s[e0]);
        emb_c[tb * 512 + e0 + 256] = f2bf(s[e0 + 256]);
    } else {
        const ushort_t* s = (const ushort_t*)Wemb + cap * 512;
        emb_c[tb * 512 + e0] = s[e0];
        emb_c[tb * 512 + e0 + 256] = s[e0 + 256];
    }
}

// ---- 64x64 MFMA tile, K=512, 256 threads (4 waves), bf16 in / fp32 acc ----
template <class AROW, class BROW, class EPI>
__device__ __forceinline__ void gemm_tile(AROW arow, BROW brow, EPI epi) {
    __shared__ __align__(16) ushort_t As[64][40];
    __shared__ __align__(16) ushort_t Bs[64][40];
    const int tid = threadIdx.x;
    const int row = tid >> 2, ks = (tid & 3) << 3;
    const int wave = tid >> 6, lane = tid & 63;
    const int quad = lane >> 4, l15 = lane & 15;
    f32x4 acc[4];
    #pragma unroll
    for (int s = 0; s < 4; ++s) acc[s] = (f32x4){0.f, 0.f, 0.f, 0.f};
    const ushort_t* ap = arow(row);
    const ushort_t* bp = brow(row);
    for (int k0 = 0; k0 < 512; k0 += 32) {
        short8 av = {0, 0, 0, 0, 0, 0, 0, 0};
        short8 bv = {0, 0, 0, 0, 0, 0, 0, 0};
        if (ap) av = *(const short8*)(ap + k0 + ks);
        if (bp) bv = *(const short8*)(bp + k0 + ks);
        __syncthreads();
        *(short8*)&As[row][ks] = av;
        *(short8*)&Bs[row][ks] = bv;
        __syncthreads();
        short8 af = *(const short8*)&As[(wave << 4) + l15][quad << 3];
        #pragma unroll
        for (int s = 0; s < 4; ++s) {
            short8 bfr = *(const short8*)&Bs[(s << 4) + l15][quad << 3];
            acc[s] = __builtin_amdgcn_mfma_f32_16x16x32_bf16(af, bfr, acc[s], 0, 0, 0);
        }
    }
    epi((wave << 4) + (quad << 2), l15, acc);
}

// ---- mean over L of features [B, F, L] -> bf16 [B, F] ----
__global__ __launch_bounds__(256) void mean_kernel(const ushort_t* __restrict__ features,
                                                   ushort_t* __restrict__ mean_bf) {
    const int b = blockIdx.x;
    const int wave = threadIdx.x >> 6, lane = threadIdx.x & 63;
    const ushort_t* fb = features + b * 512 * 196;
    for (int f = wave; f < 512; f += 4) {
        const ushort_t* r = fb + f * 196;
        float s = bf2f(r[lane]) + bf2f(r[lane + 64]) + bf2f(r[lane + 128]);
        if (lane < 4) s += bf2f(r[lane + 192]);
        s = wred_sum(s);
        if (lane == 0) mean_bf[b * 512 + f] = f2bf(s * (1.f / 196.f));
    }
}

// ---- h0 / c0 ----
__global__ __launch_bounds__(256) void init_kernel(
    const ushort_t* __restrict__ mean_bf, const ushort_t* __restrict__ Winh,
    const ushort_t* __restrict__ binh, const ushort_t* __restrict__ Winc,
    const ushort_t* __restrict__ binc, ushort_t* __restrict__ h_bf,
    float* __restrict__ cbuf) {
    const int n0 = blockIdx.x << 6;
    gemm_tile(
        [&](int r) { return mean_bf + r * 512; },
        [&](int r) {
            int n = n0 + r;
            return (n < 512) ? (Winh + n * 512) : (Winc + (n - 512) * 512);
        },
        [&](int mb, int l15, const f32x4* acc) {
            #pragma unroll
            for (int s = 0; s < 4; ++s) {
                int n = n0 + (s << 4) + l15;
                #pragma unroll
                for (int r = 0; r < 4; ++r) {
                    int b = mb + r;
                    if (n < 512)
                        h_bf[b * 512 + n] = f2bf(acc[s][r] + bf2f(binh[n]));
                    else
                        cbuf[b * 512 + (n - 512)] = acc[s][r] + bf2f(binc[n - 512]);
                }
            }
        });
}

// ---- en_att = feat_r @ W_enc.T + b_enc -> bf16 [12544, 512] ----
__global__ __launch_bounds__(256) void enatt_kernel(const ushort_t* __restrict__ feat,
                                                    const ushort_t* __restrict__ Wenc,
                                                    const ushort_t* __restrict__ benc,
                                                    ushort_t* __restrict__ en_att) {
    const int m0 = blockIdx.y << 6, n0 = blockIdx.x << 6;
    gemm_tile(
        [&](int r) { return feat + (m0 + r) * 512; },
        [&](int r) { return Wenc + (n0 + r) * 512; },
        [&](int mb, int l15, const f32x4* acc) {
            #pragma unroll
            for (int s = 0; s < 4; ++s) {
                int n = n0 + (s << 4) + l15;
                float bias = bf2f(benc[n]);
                #pragma unroll
                for (int r = 0; r < 4; ++r) {
                    int m = m0 + mb + r;
                    en_att[m * 512 + n] = f2bf(acc[s][r] + bias);
                }
            }
        });
}

// ---- ec[t,b,j] = emb_row @ W_ih[:, :512].T + b_ih + b_hh -> fp32 ----
__global__ __launch_bounds__(256) void ec_kernel(const ushort_t* __restrict__ emb_c,
                                                 const ushort_t* __restrict__ Wih,
                                                 const ushort_t* __restrict__ bih,
                                                 const ushort_t* __restrict__ bhh,
                                                 float* __restrict__ ec) {
    const int t = blockIdx.y, n0 = blockIdx.x << 6;
    gemm_tile(
        [&](int r) { return emb_c + (t * 64 + r) * 512; },
        [&](int r) { return Wih + (n0 + r) * 1024; },
        [&](int mb, int l15, const f32x4* acc) {
            #pragma unroll
            for (int s = 0; s < 4; ++s) {
                int j = n0 + (s << 4) + l15;
                float bias = bf2f(bih[j]) + bf2f(bhh[j]);
                #pragma unroll
                for (int r = 0; r < 4; ++r) {
                    int b = mb + r;
                    ec[(t * 64 + b) * 2048 + j] = acc[s][r] + bias;
                }
            }
        });
}

// ---- stepA: h @ [W_dec; W_fbeta; W_hh].T -> de | sigmoid(fbeta) | hh ----
__global__ __launch_bounds__(256) void stepA_kernel(
    const ushort_t* __restrict__ h_bf, const ushort_t* __restrict__ Wdec,
    const ushort_t* __restrict__ bdec, const ushort_t* __restrict__ Wfb,
    const ushort_t* __restrict__ bfb, const ushort_t* __restrict__ Whh,
    float* __restrict__ de, float* __restrict__ fgate, float* __restrict__ hh) {
    const int n0 = blockIdx.x << 6;
    gemm_tile(
        [&](int r) { return h_bf + r * 512; },
        [&](int r) {
            int n = n0 + r;
            if (n < 512) return Wdec + n * 512;
            if (n < 1024) return Wfb + (n - 512) * 512;
            return Whh + (n - 1024) * 512;
        },
        [&](int mb, int l15, const f32x4* acc) {
            #pragma unroll
            for (int s = 0; s < 4; ++s) {
                int n = n0 + (s << 4) + l15;
                #pragma unroll
                for (int r = 0; r < 4; ++r) {
                    int b = mb + r;
                    float v = acc[s][r];
                    if (n < 512)
                        de[b * 512 + n] = v + bf2f(bdec[n]);
                    else if (n < 1024)
                        fgate[b * 512 + (n - 512)] = sigmoidf_(v + bf2f(bfb[n - 512]));
                    else
                        hh[b * 2048 + (n - 1024)] = v;
                }
            }
        });
}

// ---- stepB: attention softmax + context z, per batch element ----
__global__ __launch_bounds__(256) void stepB_kernel(
    const ushort_t* __restrict__ en_att, const float* __restrict__ de,
    const ushort_t* __restrict__ wfull_c, const ushort_t* __restrict__ bfull_c,
    const ushort_t* __restrict__ feat, const float* __restrict__ fgate,
    const int* __restrict__ lengths, const int* __restrict__ flag,
    void* __restrict__ out_base, ushort_t* __restrict__ z_bf, int t) {
    const int b = blockIdx.x, tid = threadIdx.x;
    const int wave = tid >> 6, lane = tid & 63;
    const int f32o = *flag;
    const size_t aoff = 19840000ull + ((size_t)b * 31 + t) * 196;
    const bool active = (lengths[b] - 1) > t;
    if (!active) {
        if (tid < 196) {
            if (f32o) ((float*)out_base)[aoff + tid] = 0.f;
            else ((ushort_t*)out_base)[aoff + tid] = 0;
        }
        return;
    }
    __shared__ float de_s[512], wf_s[512], fullv[196], red[8];
    de_s[tid] = de[b * 512 + tid];
    de_s[tid + 256] = de[b * 512 + tid + 256];
    wf_s[tid] = bf2f(wfull_c[tid]);
    wf_s[tid + 256] = bf2f(wfull_c[tid + 256]);
    __syncthreads();
    const ushort_t* ea = en_att + b * 196 * 512;
    const float bf0 = bf2f(bfull_c[0]);
    for (int l = wave; l < 196; l += 4) {
        const ushort_t* er = ea + l * 512;
        float acc = 0.f;
        #pragma unroll
        for (int s = 0; s < 8; ++s) {
            int a = s * 64 + lane;
            float x = bf2f(er[a]) + de_s[a];
            acc += tanh_fast(x) * wf_s[a];
        }
        acc = wred_sum(acc);
        if (lane == 0) fullv[l] = acc + bf0;
    }
    __syncthreads();
    float v = (tid < 196) ? fullv[tid] : -1e30f;
    float wm = wred_max(v);
    if (lane == 0) red[wave] = wm;
    __syncthreads();
    float mx = fmaxf(fmaxf(red[0], red[1]), fmaxf(red[2], red[3]));
    float e = (tid < 196) ? __expf(v - mx) : 0.f;
    float sw = wred_sum(e);
    if (lane == 0) red[4 + wave] = sw;
    __syncthreads();
    float inv = 1.f / (red[4] + red[5] + red[6] + red[7]);
    if (tid < 196) {
        float a = e * inv;
        fullv[tid] = a;
        if (f32o) ((float*)out_base)[aoff + tid] = a;
        else ((ushort_t*)out_base)[aoff + tid] = f2bf(a);
    }
    __syncthreads();
    const ushort_t* fr = feat + b * 196 * 512;
    float z1 = 0.f, z2 = 0.f;
    for (int l = 0; l < 196; ++l) {
        float a = fullv[l];
        z1 += a * bf2f(fr[l * 512 + tid]);
        z2 += a * bf2f(fr[l * 512 + tid + 256]);
    }
    z1 *= fgate[b * 512 + tid];
    z2 *= fgate[b * 512 + tid + 256];
    z_bf[b * 512 + tid] = f2bf(z1);
    z_bf[b * 512 + tid + 256] = f2bf(z2);
}

// ---- stepC: gates = z @ W_ih[:,512:].T + ec + hh ; LSTM pointwise ----
__global__ __launch_bounds__(256) void stepC_kernel(
    const ushort_t* __restrict__ z_bf, const ushort_t* __restrict__ Wih,
    const float* __restrict__ ec, const float* __restrict__ hh,
    const int* __restrict__ lengths, float* __restrict__ cbuf,
    ushort_t* __restrict__ h_bf, ushort_t* __restrict__ H_all, int t) {
    const int nt = blockIdx.x;
    gemm_tile(
        [&](int r) { return z_bf + r * 512; },
        [&](int r) {
            int g = r >> 4, cd = r & 15;
            int j = g * 512 + nt * 16 + cd;
            return Wih + j * 1024 + 512;
        },
        [&](int mb, int l15, const f32x4* acc) {
            const int dim = (nt << 4) + l15;
            #pragma unroll
            for (int r = 0; r < 4; ++r) {
                int b = mb + r;
                int eb = (t * 64 + b) * 2048;
                int hb = b * 2048;
                float ig = acc[0][r] + ec[eb + dim] + hh[hb + dim];
                float fg = acc[1][r] + ec[eb + 512 + dim] + hh[hb + 512 + dim];
                float gg = acc[2][r] + ec[eb + 1024 + dim] + hh[hb + 1024 + dim];
                float og = acc[3][r] + ec[eb + 1536 + dim] + hh[hb + 1536 + dim];
                float co = cbuf[b * 512 + dim];
                float cn = sigmoidf_(fg) * co + sigmoidf_(ig) * tanh_fast(gg);
                float hn = sigmoidf_(og) * tanh_fast(cn);
                H_all[(t * 64 + b) * 512 + dim] = f2bf(hn);
                if (lengths[b] - 1 > t) {
                    cbuf[b * 512 + dim] = cn;
                    h_bf[b * 512 + dim] = f2bf(hn);
                }
            }
        });
}

// ---- preds = H_all @ W_out.T + b_out, ragged-masked ----
__global__ __launch_bounds__(256) void preds_kernel(
    const ushort_t* __restrict__ H_all, const ushort_t* __restrict__ Wout,
    const ushort_t* __restrict__ bout, const int* __restrict__ lengths,
    const int* __restrict__ flag, void* __restrict__ out_base) {
    const int t = blockIdx.y, n0 = blockIdx.x << 6;
    const int f32o = *flag;
    gemm_tile(
        [&](int r) { return H_all + (t * 64 + r) * 512; },
        [&](int r) -> const ushort_t* {
            int n = n0 + r;
            return (n < 10000) ? (Wout + n * 512) : (const ushort_t*)nullptr;
        },
        [&](int mb, int l15, const f32x4* acc) {
            #pragma unroll
            for (int s = 0; s < 4; ++s) {
                int n = n0 + (s << 4) + l15;
                if (n >= 10000) continue;
                float bias = bf2f(bout[n]);
                #pragma unroll
                for (int r = 0; r < 4; ++r) {
                    int b = mb + r;
                    bool act = lengths[b] > t + 1;
                    float val = act ? (acc[s][r] + bias) : 0.f;
                    size_t off = (size_t)b * 310000 + t * 10000 + n;
                    if (f32o) ((float*)out_base)[off] = val;
                    else ((ushort_t*)out_base)[off] = act ? f2bf(val) : (ushort_t)0;
                }
            }
        });
}

extern "C" void kernel_launch(void* const* d_in, const int* in_sizes, int n_in,
                              void* d_out, int out_size, void* d_ws, size_t ws_size,
                              hipStream_t stream) {
    const void* features = d_in[0];
    const int* captions = (const int*)d_in[1];
    const int* lengths = (const int*)d_in[2];
    const void* W_emb = d_in[3];

    char* ws = (char*)d_ws;
    size_t o = 0;
    auto alloc = [&](size_t bytes) {
        size_t r = o;
        o += (bytes + 255) & ~(size_t)255;
        return r;
    };
    // canonical bf16 copies
    ushort_t* feat_c  = (ushort_t*)(ws + alloc(6422528ull * 2));
    ushort_t* Wenc_c  = (ushort_t*)(ws + alloc(262144ull * 2));
    ushort_t* benc_c  = (ushort_t*)(ws + alloc(512 * 2));
    ushort_t* Wdec_c  = (ushort_t*)(ws + alloc(262144ull * 2));
    ushort_t* bdec_c  = (ushort_t*)(ws + alloc(512 * 2));
    ushort_t* wfull_c = (ushort_t*)(ws + alloc(512 * 2));
    ushort_t* bfull_c = (ushort_t*)(ws + alloc(2));
    ushort_t* Wfb_c   = (ushort_t*)(ws + alloc(262144ull * 2));
    ushort_t* bfb_c   = (ushort_t*)(ws + alloc(512 * 2));
    ushort_t* Wih_c   = (ushort_t*)(ws + alloc(2097152ull * 2));
    ushort_t* Whh_c   = (ushort_t*)(ws + alloc(1048576ull * 2));
    ushort_t* bih_c   = (ushort_t*)(ws + alloc(2048 * 2));
    ushort_t* bhh_c   = (ushort_t*)(ws + alloc(2048 * 2));
    ushort_t* Wout_c  = (ushort_t*)(ws + alloc(5120000ull * 2));
    ushort_t* bout_c  = (ushort_t*)(ws + alloc(10000 * 2));
    ushort_t* Winh_c  = (ushort_t*)(ws + alloc(262144ull * 2));
    ushort_t* binh_c  = (ushort_t*)(ws + alloc(512 * 2));
    ushort_t* Winc_c  = (ushort_t*)(ws + alloc(262144ull * 2));
    ushort_t* binc_c  = (ushort_t*)(ws + alloc(512 * 2));
    ushort_t* emb_c   = (ushort_t*)(ws + alloc(1984ull * 512 * 2));
    // intermediates
    ushort_t* en_att  = (ushort_t*)(ws + alloc(12544ull * 512 * 2));
    float*    ec      = (float*)(ws + alloc(1984ull * 2048 * 4));
    ushort_t* H_all   = (ushort_t*)(ws + alloc(1984ull * 512 * 2));
    ushort_t* h_bf    = (ushort_t*)(ws + alloc(64 * 512 * 2));
    float*    cbuf    = (float*)(ws + alloc(64 * 512 * 4));
    float*    de      = (float*)(ws + alloc(64 * 512 * 4));
    float*    fgate   = (float*)(ws + alloc(64 * 512 * 4));
    float*    hh      = (float*)(ws + alloc(64ull * 2048 * 4));
    ushort_t* z_bf    = (ushort_t*)(ws + alloc(64 * 512 * 2));
    ushort_t* mean_bf = (ushort_t*)(ws + alloc(64 * 512 * 2));
    int*      flag    = (int*)(ws + alloc(256));

    detect_kernel<<<1, 64, 0, stream>>>((const unsigned*)features, flag);

    CvtArgs ca;
    const void* srcs[NCVT] = {features, d_in[4], d_in[5], d_in[6], d_in[7], d_in[8],
                              d_in[9], d_in[10], d_in[11], d_in[12], d_in[13], d_in[14],
                              d_in[15], d_in[16], d_in[17], d_in[18], d_in[19], d_in[20],
                              d_in[21]};
    void* dsts[NCVT] = {feat_c, Wenc_c, benc_c, Wdec_c, bdec_c, wfull_c, bfull_c,
                        Wfb_c, bfb_c, Wih_c, Whh_c, bih_c, bhh_c, Wout_c, bout_c,
                        Winh_c, binh_c, Winc_c, binc_c};
    int ns[NCVT] = {6422528, 262144, 512, 262144, 512, 512, 1, 262144, 512,
                    2097152, 1048576, 2048, 2048, 5120000, 10000, 262144, 512,
                    262144, 512};
    for (int i = 0; i < NCVT; ++i) {
        ca.src[i] = srcs[i];
        ca.dst[i] = dsts[i];
        ca.n[i] = ns[i];
    }
    convert_kernel<<<dim3(3136, NCVT), 256, 0, stream>>>(ca, flag);
    embrows_kernel<<<1984, 256, 0, stream>>>(W_emb, captions, flag, emb_c);

    mean_kernel<<<64, 256, 0, stream>>>(feat_c, mean_bf);
    init_kernel<<<16, 256, 0, stream>>>(mean_bf, Winh_c, binh_c, Winc_c, binc_c,
                                        h_bf, cbuf);
    enatt_kernel<<<dim3(8, 196), 256, 0, stream>>>(feat_c, Wenc_c, benc_c, en_att);
    ec_kernel<<<dim3(32, 31), 256, 0, stream>>>(emb_c, Wih_c, bih_c, bhh_c, ec);

    for (int t = 0; t < 31; ++t) {
        stepA_kernel<<<48, 256, 0, stream>>>(h_bf, Wdec_c, bdec_c, Wfb_c, bfb_c,
                                             Whh_c, de, fgate, hh);
        stepB_kernel<<<64, 256, 0, stream>>>(en_att, de, wfull_c, bfull_c, feat_c,
                                             fgate, lengths, flag, d_out, z_bf, t);
        stepC_kernel<<<32, 256, 0, stream>>>(z_bf, Wih_c, ec, hh, lengths, cbuf,
                                             h_bf, H_all, t);
    }
    preds_kernel<<<dim3(157, 31), 256, 0, stream>>>(H_all, Wout_c, bout_c, lengths,
                                                    flag, d_out);
}